// Round 11
// baseline (235.975 us; speedup 1.0000x reference)
//
#include <hip/hip_runtime.h>
#include <hip/hip_cooperative_groups.h>

namespace cg = cooperative_groups;

#define LRELU(v) ((v) >= 0.f ? (v) : 0.2f*(v))

// ---- conv1: named-register row access (rp = per-sample ro pointer) --------
#define ROROW(P, RB) \
    const float P##0=rp[(RB)+0], P##1=rp[(RB)+1], P##2=rp[(RB)+2], \
        P##3=rp[(RB)+3], P##4=rp[(RB)+4], P##5=rp[(RB)+5], \
        P##6=rp[(RB)+6], P##7=rp[(RB)+7], P##8=rp[(RB)+8];

#define C1X(X0,X1,X2,X3) \
    (wa.x*A##X0 + wa.y*A##X1 + wa.z*A##X2 + wa.w*A##X3 \
   + wb.x*B##X0 + wb.y*B##X1 + wb.z*B##X2 + wb.w*B##X3 \
   + wc.x*C##X0 + wc.y*C##X1 + wc.z*C##X2 + wc.w*C##X3 \
   + wd.x*D##X0 + wd.y*D##X1 + wd.z*D##X2 + wd.w*D##X3)

// ---- conv2: named-register h-row access ----------------------------------
#define E0 q0.x
#define E1 q0.y
#define E2 q0.z
#define E3 q0.w
#define E4 q1.x
#define E5 q1.y
#define E6 q1.z
#define E7 q1.w
#define E8 q2.x
#define E9 q2.y
#define E10 q2.z
#define E11 q2.w
#define E12 q3.x
#define E13 q3.y
#define E14 q3.z
#define E15 q3.w
#define E16 q4.x
#define E17 q4.y
#define E18 q4.z
#define E19 q4.w
#define E20 q5.x
#define E21 q5.y
#define E22 q5.z
#define E23 q5.w
#define E24 q6.x
#define E25 q6.y
#define E26 q6.z
#define E27 q6.w
#define E28 q7.x
#define E29 q7.y
#define E30 q7.z
#define E31 q7.w
#define E32 q8.x
#define E33 q8.y
#define E34 q8.z
#define E35 q8.w

#define AX(ACC, A, B, C, D) ACC += w.x*E##A + w.y*E##B + w.z*E##C + w.w*E##D;

#define KY0(P) { AX(P##0, 0,1,2,3)    AX(P##1, 1,2,3,4)    AX(P##2, 2,3,4,5) \
                 AX(P##3, 6,7,8,9)    AX(P##4, 7,8,9,10)   AX(P##5, 8,9,10,11) \
                 AX(P##6, 12,13,14,15) AX(P##7, 13,14,15,16) AX(P##8, 14,15,16,17) }
#define KY1(P) { AX(P##0, 6,7,8,9)    AX(P##1, 7,8,9,10)   AX(P##2, 8,9,10,11) \
                 AX(P##3, 12,13,14,15) AX(P##4, 13,14,15,16) AX(P##5, 14,15,16,17) \
                 AX(P##6, 18,19,20,21) AX(P##7, 19,20,21,22) AX(P##8, 20,21,22,23) }
#define KY2(P) { AX(P##0, 12,13,14,15) AX(P##1, 13,14,15,16) AX(P##2, 14,15,16,17) \
                 AX(P##3, 18,19,20,21) AX(P##4, 19,20,21,22) AX(P##5, 20,21,22,23) \
                 AX(P##6, 24,25,26,27) AX(P##7, 25,26,27,28) AX(P##8, 26,27,28,29) }
#define KY3(P) { AX(P##0, 18,19,20,21) AX(P##1, 19,20,21,22) AX(P##2, 20,21,22,23) \
                 AX(P##3, 24,25,26,27) AX(P##4, 25,26,27,28) AX(P##5, 26,27,28,29) \
                 AX(P##6, 30,31,32,33) AX(P##7, 31,32,33,34) AX(P##8, 32,33,34,35) }

#define RED9(P, M) \
    P##0+=__shfl_xor(P##0,M); P##1+=__shfl_xor(P##1,M); P##2+=__shfl_xor(P##2,M); \
    P##3+=__shfl_xor(P##3,M); P##4+=__shfl_xor(P##4,M); P##5+=__shfl_xor(P##5,M); \
    P##6+=__shfl_xor(P##6,M); P##7+=__shfl_xor(P##7,M); P##8+=__shfl_xor(P##8,M);

#define S16(P0, P1, P2, P3) \
  (fabsf(v0.x-P0.x)+fabsf(v0.y-P0.y)+fabsf(v0.z-P0.z)+fabsf(v0.w-P0.w) \
  +fabsf(v1.x-P1.x)+fabsf(v1.y-P1.y)+fabsf(v1.z-P1.z)+fabsf(v1.w-P1.w) \
  +fabsf(v2.x-P2.x)+fabsf(v2.y-P2.y)+fabsf(v2.z-P2.z)+fabsf(v2.w-P2.w) \
  +fabsf(v3.x-P3.x)+fabsf(v3.y-P3.y)+fabsf(v3.z-P3.z)+fabsf(v3.w-P3.w))

// ===================== fused cooperative kernel (grid 256) =================
// Phases: A conv+f (2 samples/blk) | B M=F@T (2 tiles/blk) | C pairwise
// (4 chunks of 8 i-rows) | D MLP (2 samples/blk). LDS max 18.3KB.
__global__ __launch_bounds__(256) void fused_kernel(
    const float* __restrict__ readout, const float* __restrict__ energy,
    const float* __restrict__ w1, const float* __restrict__ w2,
    const float* __restrict__ Tm, const float* __restrict__ W1,
    const float* __restrict__ b1v, const float* __restrict__ W2,
    const float* __restrict__ b2v,
    float* __restrict__ f_ws, float* __restrict__ Mw,
    float* __restrict__ o_part, float* __restrict__ W1T,
    float* __restrict__ out)
{
    __shared__ float smem[4576];         // 18.3 KB, aliased per phase
    const int bid = blockIdx.x;
    const int t = threadIdx.x;
    cg::grid_group grid = cg::this_grid();

    // ---------------- Phase A: conv stack, samples 2*bid, 2*bid+1 ---------
    {
        float* ro = smem;                // [2][81]
        float* h1 = smem + 192;          // [2][1152]

        if (t < 162) ro[t] = readout[bid*162 + t];
        __syncthreads();

        if (t < 128) {                   // reco_energy
            const int es = t >> 6, l = t & 63;
            float v = ro[es*81 + l];
            if (l < 17) v += ro[es*81 + l + 64];
            #pragma unroll
            for (int m = 32; m; m >>= 1) v += __shfl_down(v, m);
            if (l == 0) f_ws[(2*bid+es)*577 + 576] = fabsf(v - energy[2*bid+es]);
        }

        for (int idx = t; idx < 384; idx += 256) {   // conv1
            const int sA = (idx >= 192) ? 1 : 0;
            const int rem = idx - sA*192;
            const int oc1 = rem & 31, y = rem >> 5;
            const float* rp = ro + sA*81;
            const float4* wp4 = (const float4*)&w1[oc1*16];
            const float4 wa = wp4[0], wb = wp4[1], wc = wp4[2], wd = wp4[3];
            const int rb0 = y*9;
            ROROW(A, rb0)
            ROROW(B, rb0+9)
            ROROW(C, rb0+18)
            ROROW(D, rb0+27)
            float* hp = &h1[sA*1152 + oc1*36 + y*6];
            float v;
            v = C1X(0,1,2,3); hp[0] = LRELU(v);
            v = C1X(1,2,3,4); hp[1] = LRELU(v);
            v = C1X(2,3,4,5); hp[2] = LRELU(v);
            v = C1X(3,4,5,6); hp[3] = LRELU(v);
            v = C1X(4,5,6,7); hp[4] = LRELU(v);
            v = C1X(5,6,7,8); hp[5] = LRELU(v);
        }
        __syncthreads();

        // conv2: s2 = t>>7, ocp = (t&127)>>2 (2 oc), ich = t&3 (8 ic each)
        const int s2 = t >> 7, lt = t & 127;
        const int ocp = lt >> 2, ich = t & 3;
        const int oca = ocp*2, ocbb = oca + 1;
        float a0=0.f,a1=0.f,a2=0.f,a3=0.f,a4=0.f,a5=0.f,a6=0.f,a7=0.f,a8=0.f;
        float g0=0.f,g1=0.f,g2=0.f,g3=0.f,g4=0.f,g5=0.f,g6=0.f,g7=0.f,g8=0.f;
        const float* hb = h1 + s2*1152;
        #pragma unroll
        for (int k = 0; k < 8; k++) {
            const int ic = ich + k*4;
            const float4* hp = (const float4*)&hb[ic*36];
            const float4 q0=hp[0], q1=hp[1], q2=hp[2], q3=hp[3], q4=hp[4],
                         q5=hp[5], q6=hp[6], q7=hp[7], q8=hp[8];
            const float4* wpa = (const float4*)&w2[oca*512 + ic*16];
            const float4* wpb = (const float4*)&w2[ocbb*512 + ic*16];
            { float4 w = wpa[0]; KY0(a) }
            { float4 w = wpa[1]; KY1(a) }
            { float4 w = wpa[2]; KY2(a) }
            { float4 w = wpa[3]; KY3(a) }
            { float4 w = wpb[0]; KY0(g) }
            { float4 w = wpb[1]; KY1(g) }
            { float4 w = wpb[2]; KY2(g) }
            { float4 w = wpb[3]; KY3(g) }
        }
        RED9(a,1) RED9(a,2) RED9(g,1) RED9(g,2)

        if (ich == 0) {
            const int n = 2*bid + s2;
            float* fa = &f_ws[n*577 + oca*9];
            float* fb = &f_ws[n*577 + ocbb*9];
            float v;
            v=a0; fa[0]=LRELU(v); v=a1; fa[1]=LRELU(v); v=a2; fa[2]=LRELU(v);
            v=a3; fa[3]=LRELU(v); v=a4; fa[4]=LRELU(v); v=a5; fa[5]=LRELU(v);
            v=a6; fa[6]=LRELU(v); v=a7; fa[7]=LRELU(v); v=a8; fa[8]=LRELU(v);
            v=g0; fb[0]=LRELU(v); v=g1; fb[1]=LRELU(v); v=g2; fb[2]=LRELU(v);
            v=g3; fb[3]=LRELU(v); v=g4; fb[4]=LRELU(v); v=g5; fb[5]=LRELU(v);
            v=g6; fb[6]=LRELU(v); v=g7; fb[7]=LRELU(v); v=g8; fb[8]=LRELU(v);
        }

        if (bid < 8) {                   // W1 transpose
            for (int idx = t; idx < 2436; idx += 256) {
                const int g = bid*2436 + idx;
                const int u = g & 31, a = g >> 5;
                W1T[g] = W1[u*609 + a];
            }
        }
    }
    grid.sync();

    // ---------------- Phase B: M = F @ T, 2 tiles of (8r x 64c) -----------
    {
        float* redB = smem;              // [ks(4)][row(8)][col(64)]
        #pragma unroll
        for (int it = 0; it < 2; it++) {
            const int tt = bid*2 + it;
            const int rb = tt >> 3, cb = tt & 7;
            const int colB = cb*64 + (t & 63);
            const int r0B = rb*8;
            const int ks = __builtin_amdgcn_readfirstlane(t >> 6);
            const int k0 = ks*145;
            const int k1 = (k0 + 145 < 577) ? k0 + 145 : 577;
            float c0=0.f,c1=0.f,c2=0.f,c3=0.f,c4=0.f,c5=0.f,c6=0.f,c7=0.f;
            const float* fbase = f_ws + r0B*577;
            for (int k = k0; k < k1; ++k) {
                const float tv = Tm[k*512 + colB];
                const float* fr = fbase + k;
                c0 += fr[0]*tv;    c1 += fr[577]*tv;  c2 += fr[1154]*tv; c3 += fr[1731]*tv;
                c4 += fr[2308]*tv; c5 += fr[2885]*tv; c6 += fr[3462]*tv; c7 += fr[4039]*tv;
            }
            const int cl = t & 63;
            redB[ks*512 +   0 + cl] = c0;  redB[ks*512 +  64 + cl] = c1;
            redB[ks*512 + 128 + cl] = c2;  redB[ks*512 + 192 + cl] = c3;
            redB[ks*512 + 256 + cl] = c4;  redB[ks*512 + 320 + cl] = c5;
            redB[ks*512 + 384 + cl] = c6;  redB[ks*512 + 448 + cl] = c7;
            __syncthreads();
            for (int idx = t; idx < 512; idx += 256) {
                const float v = redB[idx] + redB[512+idx] + redB[1024+idx] + redB[1536+idx];
                Mw[(r0B + (idx >> 6))*512 + cb*64 + (idx & 63)] = v;
            }
            __syncthreads();
        }
    }
    grid.sync();

    // ---------------- Phase C: pairwise exp(-L1) --------------------------
    // jt = bid>>4 (32 j's), isp = bid&15 (32 i's, 4 chunks of 8)
    {
        const int jt  = bid >> 4;
        const int isp = bid & 15;
        const int b = t & 31, jl = t >> 5;
        const int j0 = jt * 32;
        float* mi = smem;                // 8 x 572 padded

        float4 mA0,mA1,mA2,mA3, mB0,mB1,mB2,mB3, mC0,mC1,mC2,mC3, mD0,mD1,mD2,mD3;
        { const float4* p_ = (const float4*)&Mw[(j0+jl   )*512 + b*16];
          mA0=p_[0]; mA1=p_[1]; mA2=p_[2]; mA3=p_[3]; }
        { const float4* p_ = (const float4*)&Mw[(j0+jl+ 8)*512 + b*16];
          mB0=p_[0]; mB1=p_[1]; mB2=p_[2]; mB3=p_[3]; }
        { const float4* p_ = (const float4*)&Mw[(j0+jl+16)*512 + b*16];
          mC0=p_[0]; mC1=p_[1]; mC2=p_[2]; mC3=p_[3]; }
        { const float4* p_ = (const float4*)&Mw[(j0+jl+24)*512 + b*16];
          mD0=p_[0]; mD1=p_[1]; mD2=p_[2]; mD3=p_[3]; }

        float acc0 = 0.f, acc1 = 0.f, acc2 = 0.f, acc3 = 0.f;
        const int lbase = b*16 + ((b>>1)<<2);

        for (int chunk = 0; chunk < 4; chunk++) {
            const int i0 = isp*32 + chunk*8;
            #pragma unroll
            for (int k = 0; k < 4; k++) {
                const int q = k*256 + t;       // 0..1023
                const int r = q >> 7;
                const int x = (q & 127) * 4;
                float4 v = *(const float4*)&Mw[(i0+r)*512 + x];
                *(float4*)&mi[r*572 + x + ((x>>5)<<2)] = v;
            }
            __syncthreads();
            #pragma unroll
            for (int r = 0; r < 8; r++) {
                const float4* q_ = (const float4*)&mi[r*572 + lbase];
                const float4 v0 = q_[0], v1 = q_[1], v2 = q_[2], v3 = q_[3];
                acc0 += __expf(-(S16(mA0,mA1,mA2,mA3)));
                acc1 += __expf(-(S16(mB0,mB1,mB2,mB3)));
                acc2 += __expf(-(S16(mC0,mC1,mC2,mC3)));
                acc3 += __expf(-(S16(mD0,mD1,mD2,mD3)));
            }
            __syncthreads();
        }
        const int ob = isp*16384 + b;
        o_part[ob + (j0+jl   )*32] = acc0;
        o_part[ob + (j0+jl+8 )*32] = acc1;
        o_part[ob + (j0+jl+16)*32] = acc2;
        o_part[ob + (j0+jl+24)*32] = acc3;
    }
    grid.sync();

    // ---------------- Phase D: MLP head, samples 2*bid, 2*bid+1 -----------
    {
        float* xs   = smem;              // [2][640]
        float* redD = smem + 1280;       // [2][128]
        const int s2 = t >> 7, lt = t & 127;
        const int j = 2*bid + s2;
        const int u = lt & 31, gD = lt >> 5;   // gD in 0..3

        for (int a = lt; a < 577; a += 128) xs[s2*640 + a] = f_ws[j*577 + a];
        {
            float ov = 0.f;
            #pragma unroll
            for (int k = 0; k < 4; k++)
                ov += o_part[(gD + 4*k)*16384 + j*32 + u];
            redD[s2*128 + lt] = ov;
        }
        __syncthreads();
        if (lt < 32) {
            xs[s2*640 + 577 + lt] = redD[s2*128 + lt] + redD[s2*128 + lt + 32]
                                  + redD[s2*128 + lt + 64] + redD[s2*128 + lt + 96];
        }
        __syncthreads();

        float p = 0.f;
        #pragma unroll 4
        for (int a = gD; a < 609; a += 4)
            p += xs[s2*640 + a] * W1T[a*32 + u];
        redD[s2*128 + lt] = p;
        __syncthreads();

        if (lt < 32) {
            float hid = redD[s2*128 + lt] + redD[s2*128 + lt + 32]
                      + redD[s2*128 + lt + 64] + redD[s2*128 + lt + 96];
            hid += b1v[lt];
            hid = LRELU(hid);
            float pr = hid * W2[lt];
            #pragma unroll
            for (int mk = 16; mk; mk >>= 1) pr += __shfl_xor(pr, mk);
            if (lt == 0) out[j] = 1.f / (1.f + __expf(-(pr + b2v[0])));
        }
    }
}

// =================== fallback: round-9 four-kernel path ====================
__global__ __launch_bounds__(256) void convf_kernel(
    const float* __restrict__ readout, const float* __restrict__ energy,
    const float* __restrict__ w1, const float* __restrict__ w2,
    const float* __restrict__ W1, float* __restrict__ f_ws,
    float* __restrict__ W1T)
{
    const int bid = blockIdx.x;
    const int n   = bid >> 1;
    const int och = bid & 1;
    const int oc0 = och << 5;
    const int t = threadIdx.x;
    __shared__ float ro[81];
    __shared__ float h1[1152];

    if (t < 81) ro[t] = readout[n*81 + t];
    __syncthreads();

    if (och == 0 && t < 64) {
        float v = ro[t];
        if (t < 17) v += ro[t + 64];
        #pragma unroll
        for (int m = 32; m; m >>= 1) v += __shfl_down(v, m);
        if (t == 0) f_ws[n*577 + 576] = fabsf(v - energy[n]);
    }

    if (t < 192) {
        const int oc1 = t & 31, y = t >> 5;
        const float* rp = ro;
        const float4* wp4 = (const float4*)&w1[oc1*16];
        const float4 wa = wp4[0], wb = wp4[1], wc = wp4[2], wd = wp4[3];
        const int rb0 = y*9;
        ROROW(A, rb0)
        ROROW(B, rb0+9)
        ROROW(C, rb0+18)
        ROROW(D, rb0+27)
        float* hp = &h1[oc1*36 + y*6];
        float v;
        v = C1X(0,1,2,3); hp[0] = LRELU(v);
        v = C1X(1,2,3,4); hp[1] = LRELU(v);
        v = C1X(2,3,4,5); hp[2] = LRELU(v);
        v = C1X(3,4,5,6); hp[3] = LRELU(v);
        v = C1X(4,5,6,7); hp[4] = LRELU(v);
        v = C1X(5,6,7,8); hp[5] = LRELU(v);
    }
    __syncthreads();

    const int ocp = t >> 4, ich = t & 15;
    const int oca = oc0 + ocp*2, ocbb = oca + 1;
    float a0=0.f,a1=0.f,a2=0.f,a3=0.f,a4=0.f,a5=0.f,a6=0.f,a7=0.f,a8=0.f;
    float g0=0.f,g1=0.f,g2=0.f,g3=0.f,g4=0.f,g5=0.f,g6=0.f,g7=0.f,g8=0.f;

    #pragma unroll
    for (int k = 0; k < 2; k++) {
        const int ic = ich + k*16;
        const float4* hp = (const float4*)&h1[ic*36];
        const float4 q0=hp[0], q1=hp[1], q2=hp[2], q3=hp[3], q4=hp[4],
                     q5=hp[5], q6=hp[6], q7=hp[7], q8=hp[8];
        const float4* wpa = (const float4*)&w2[oca*512 + ic*16];
        const float4* wpb = (const float4*)&w2[ocbb*512 + ic*16];
        { float4 w = wpa[0]; KY0(a) }
        { float4 w = wpa[1]; KY1(a) }
        { float4 w = wpa[2]; KY2(a) }
        { float4 w = wpa[3]; KY3(a) }
        { float4 w = wpb[0]; KY0(g) }
        { float4 w = wpb[1]; KY1(g) }
        { float4 w = wpb[2]; KY2(g) }
        { float4 w = wpb[3]; KY3(g) }
    }
    RED9(a,1) RED9(a,2) RED9(a,4) RED9(a,8)
    RED9(g,1) RED9(g,2) RED9(g,4) RED9(g,8)

    if (ich == 0) {
        float* fa = &f_ws[n*577 + oca*9];
        float* fb = &f_ws[n*577 + ocbb*9];
        float v;
        v=a0; fa[0]=LRELU(v); v=a1; fa[1]=LRELU(v); v=a2; fa[2]=LRELU(v);
        v=a3; fa[3]=LRELU(v); v=a4; fa[4]=LRELU(v); v=a5; fa[5]=LRELU(v);
        v=a6; fa[6]=LRELU(v); v=a7; fa[7]=LRELU(v); v=a8; fa[8]=LRELU(v);
        v=g0; fb[0]=LRELU(v); v=g1; fb[1]=LRELU(v); v=g2; fb[2]=LRELU(v);
        v=g3; fb[3]=LRELU(v); v=g4; fb[4]=LRELU(v); v=g5; fb[5]=LRELU(v);
        v=g6; fb[6]=LRELU(v); v=g7; fb[7]=LRELU(v); v=g8; fb[8]=LRELU(v);
    }

    if (bid < 8) {
        for (int idx = t; idx < 2436; idx += 256) {
            const int g = bid*2436 + idx;
            const int u = g & 31, a = g >> 5;
            W1T[g] = W1[u*609 + a];
        }
    }
}

__global__ __launch_bounds__(256) void mgemm_kernel(
    const float* __restrict__ F, const float* __restrict__ T,
    float* __restrict__ M)
{
    const int rb = blockIdx.x >> 3;
    const int cb = blockIdx.x & 7;
    const int t = threadIdx.x;
    const int col = cb*64 + (t & 63);
    const int r0 = rb*8 + (t >> 6)*2;
    const int r0u = __builtin_amdgcn_readfirstlane(r0);
    const float* f0 = F + r0u*577;
    const float* f1 = f0 + 577;
    const float* Tc = T + col;
    float a0 = 0.f, a1 = 0.f;
    #pragma unroll 4
    for (int a = 0; a < 576; a += 4) {
        const float t0 = Tc[(a+0)*512];
        const float t1 = Tc[(a+1)*512];
        const float t2 = Tc[(a+2)*512];
        const float t3 = Tc[(a+3)*512];
        a0 += f0[a]*t0 + f0[a+1]*t1 + f0[a+2]*t2 + f0[a+3]*t3;
        a1 += f1[a]*t0 + f1[a+1]*t1 + f1[a+2]*t2 + f1[a+3]*t3;
    }
    {
        const float tv = Tc[576*512];
        a0 += f0[576]*tv;
        a1 += f1[576]*tv;
    }
    M[(r0+0)*512 + col] = a0;
    M[(r0+1)*512 + col] = a1;
}

__global__ __launch_bounds__(256) void pairwise_kernel(
    const float* __restrict__ Mw, float* __restrict__ o_part) // (16,512,32)
{
    const int jt  = blockIdx.x >> 4;
    const int isp = blockIdx.x & 15;
    const int t = threadIdx.x;
    const int b = t & 31, jl = t >> 5;
    const int j0 = jt * 32;
    __shared__ float mi[8*572];

    float4 mA0,mA1,mA2,mA3, mB0,mB1,mB2,mB3, mC0,mC1,mC2,mC3, mD0,mD1,mD2,mD3;
    { const float4* p_ = (const float4*)&Mw[(j0+jl   )*512 + b*16];
      mA0=p_[0]; mA1=p_[1]; mA2=p_[2]; mA3=p_[3]; }
    { const float4* p_ = (const float4*)&Mw[(j0+jl+ 8)*512 + b*16];
      mB0=p_[0]; mB1=p_[1]; mB2=p_[2]; mB3=p_[3]; }
    { const float4* p_ = (const float4*)&Mw[(j0+jl+16)*512 + b*16];
      mC0=p_[0]; mC1=p_[1]; mC2=p_[2]; mC3=p_[3]; }
    { const float4* p_ = (const float4*)&Mw[(j0+jl+24)*512 + b*16];
      mD0=p_[0]; mD1=p_[1]; mD2=p_[2]; mD3=p_[3]; }

    float acc0 = 0.f, acc1 = 0.f, acc2 = 0.f, acc3 = 0.f;
    const int lbase = b*16 + ((b>>1)<<2);

    for (int chunk = 0; chunk < 4; chunk++) {
        const int i0 = isp*32 + chunk*8;
        #pragma unroll
        for (int k = 0; k < 4; k++) {
            const int q = k*256 + t;
            const int r = q >> 7;
            const int x = (q & 127) * 4;
            float4 v = *(const float4*)&Mw[(i0+r)*512 + x];
            *(float4*)&mi[r*572 + x + ((x>>5)<<2)] = v;
        }
        __syncthreads();
        #pragma unroll
        for (int r = 0; r < 8; r++) {
            const float4* q_ = (const float4*)&mi[r*572 + lbase];
            const float4 v0 = q_[0], v1 = q_[1], v2 = q_[2], v3 = q_[3];
            acc0 += __expf(-(S16(mA0,mA1,mA2,mA3)));
            acc1 += __expf(-(S16(mB0,mB1,mB2,mB3)));
            acc2 += __expf(-(S16(mC0,mC1,mC2,mC3)));
            acc3 += __expf(-(S16(mD0,mD1,mD2,mD3)));
        }
        __syncthreads();
    }
    const int ob = isp*16384 + b;
    o_part[ob + (j0+jl   )*32] = acc0;
    o_part[ob + (j0+jl+8 )*32] = acc1;
    o_part[ob + (j0+jl+16)*32] = acc2;
    o_part[ob + (j0+jl+24)*32] = acc3;
}

__global__ __launch_bounds__(256) void mlp_kernel(
    const float* __restrict__ f, const float* __restrict__ o_part,
    const float* __restrict__ W1T, const float* __restrict__ b1v,
    const float* __restrict__ W2, const float* __restrict__ b2v,
    float* __restrict__ out)
{
    const int j = blockIdx.x;
    const int t = threadIdx.x;
    __shared__ float xs[609];
    __shared__ float red[256];

    for (int a = t; a < 577; a += 256) xs[a] = f[j*577 + a];
    {
        const int bb = t & 31, g = t >> 5;
        float ov = 0.f;
        #pragma unroll
        for (int k = 0; k < 2; k++)
            ov += o_part[(g + 8*k)*16384 + j*32 + bb];
        red[t] = ov;
    }
    __syncthreads();
    if (t < 32) {
        float ov = 0.f;
        #pragma unroll
        for (int g = 0; g < 8; g++) ov += red[t + g*32];
        xs[577 + t] = ov;
    }
    __syncthreads();

    const int u = t & 31, seg = t >> 5;
    float p = 0.f;
    #pragma unroll 4
    for (int a = seg; a < 609; a += 8)
        p += xs[a] * W1T[a*32 + u];
    red[t] = p;
    __syncthreads();

    if (t < 32) {
        float hid = red[t];
        #pragma unroll
        for (int s = 1; s < 8; s++) hid += red[t + s*32];
        hid += b1v[t];
        hid = LRELU(hid);
        float pr = hid * W2[t];
        #pragma unroll
        for (int mk = 16; mk; mk >>= 1) pr += __shfl_xor(pr, mk);
        if (t == 0) out[j] = 1.f / (1.f + __expf(-(pr + b2v[0])));
    }
}

extern "C" void kernel_launch(void* const* d_in, const int* in_sizes, int n_in,
                              void* d_out, int out_size, void* d_ws, size_t ws_size,
                              hipStream_t stream) {
    const float* readout = (const float*)d_in[0];
    const float* energy  = (const float*)d_in[1];
    const float* w1      = (const float*)d_in[2];
    const float* w2      = (const float*)d_in[3];
    const float* Tm      = (const float*)d_in[4];
    const float* W1      = (const float*)d_in[5];
    const float* b1v     = (const float*)d_in[6];
    const float* W2      = (const float*)d_in[7];
    const float* b2v     = (const float*)d_in[8];
    float* out = (float*)d_out;

    char* ws = (char*)d_ws;
    float* f_ws   = (float*)(ws);                                       // 512*577
    float* M_ws   = (float*)(ws + 512*577*4);                           // 512*512
    float* o_ws   = (float*)(ws + 512*577*4 + 512*512*4);               // 16*512*32
    float* W1T_ws = (float*)(ws + 512*577*4 + 512*512*4 + 16*512*32*4); // 609*32

    void* args[] = {
        (void*)&readout, (void*)&energy, (void*)&w1, (void*)&w2, (void*)&Tm,
        (void*)&W1, (void*)&b1v, (void*)&W2, (void*)&b2v,
        (void*)&f_ws, (void*)&M_ws, (void*)&o_ws, (void*)&W1T_ws, (void*)&out
    };
    hipError_t err = hipLaunchCooperativeKernel((void*)fused_kernel, dim3(256),
                                                dim3(256), args, 0, stream);
    if (err != hipSuccess) {
        // fallback: known-good 4-kernel path (o_part reinterpreted as 16 parts
        // by pairwise/mlp pair below -- self-consistent)
        convf_kernel   <<<1024, 256, 0, stream>>>(readout, energy, w1, w2, W1, f_ws, W1T_ws);
        mgemm_kernel   <<<512, 256, 0, stream>>>(f_ws, Tm, M_ws);
        pairwise_kernel<<<256, 256, 0, stream>>>(M_ws, o_ws);
        mlp_kernel     <<<512, 256, 0, stream>>>(f_ws, o_ws, W1T_ws, b1v, W2, b2v, out);
    }
}

// Round 12
// 185.638 us; speedup vs baseline: 1.2712x; 1.2712x over previous
//
#include <hip/hip_runtime.h>
#include <hip/hip_cooperative_groups.h>

namespace cg = cooperative_groups;

#define LRELU(v) ((v) >= 0.f ? (v) : 0.2f*(v))

// ---- conv1: named-register row access (rp = per-sample ro pointer) --------
#define ROROW(P, RB) \
    const float P##0=rp[(RB)+0], P##1=rp[(RB)+1], P##2=rp[(RB)+2], \
        P##3=rp[(RB)+3], P##4=rp[(RB)+4], P##5=rp[(RB)+5], \
        P##6=rp[(RB)+6], P##7=rp[(RB)+7], P##8=rp[(RB)+8];

#define C1X(X0,X1,X2,X3) \
    (wa.x*A##X0 + wa.y*A##X1 + wa.z*A##X2 + wa.w*A##X3 \
   + wb.x*B##X0 + wb.y*B##X1 + wb.z*B##X2 + wb.w*B##X3 \
   + wc.x*C##X0 + wc.y*C##X1 + wc.z*C##X2 + wc.w*C##X3 \
   + wd.x*D##X0 + wd.y*D##X1 + wd.z*D##X2 + wd.w*D##X3)

// ---- conv2: named-register h-row access ----------------------------------
#define E0 q0.x
#define E1 q0.y
#define E2 q0.z
#define E3 q0.w
#define E4 q1.x
#define E5 q1.y
#define E6 q1.z
#define E7 q1.w
#define E8 q2.x
#define E9 q2.y
#define E10 q2.z
#define E11 q2.w
#define E12 q3.x
#define E13 q3.y
#define E14 q3.z
#define E15 q3.w
#define E16 q4.x
#define E17 q4.y
#define E18 q4.z
#define E19 q4.w
#define E20 q5.x
#define E21 q5.y
#define E22 q5.z
#define E23 q5.w
#define E24 q6.x
#define E25 q6.y
#define E26 q6.z
#define E27 q6.w
#define E28 q7.x
#define E29 q7.y
#define E30 q7.z
#define E31 q7.w
#define E32 q8.x
#define E33 q8.y
#define E34 q8.z
#define E35 q8.w

#define AX(ACC, A, B, C, D) ACC += w.x*E##A + w.y*E##B + w.z*E##C + w.w*E##D;

#define KY0(P) { AX(P##0, 0,1,2,3)    AX(P##1, 1,2,3,4)    AX(P##2, 2,3,4,5) \
                 AX(P##3, 6,7,8,9)    AX(P##4, 7,8,9,10)   AX(P##5, 8,9,10,11) \
                 AX(P##6, 12,13,14,15) AX(P##7, 13,14,15,16) AX(P##8, 14,15,16,17) }
#define KY1(P) { AX(P##0, 6,7,8,9)    AX(P##1, 7,8,9,10)   AX(P##2, 8,9,10,11) \
                 AX(P##3, 12,13,14,15) AX(P##4, 13,14,15,16) AX(P##5, 14,15,16,17) \
                 AX(P##6, 18,19,20,21) AX(P##7, 19,20,21,22) AX(P##8, 20,21,22,23) }
#define KY2(P) { AX(P##0, 12,13,14,15) AX(P##1, 13,14,15,16) AX(P##2, 14,15,16,17) \
                 AX(P##3, 18,19,20,21) AX(P##4, 19,20,21,22) AX(P##5, 20,21,22,23) \
                 AX(P##6, 24,25,26,27) AX(P##7, 25,26,27,28) AX(P##8, 26,27,28,29) }
#define KY3(P) { AX(P##0, 18,19,20,21) AX(P##1, 19,20,21,22) AX(P##2, 20,21,22,23) \
                 AX(P##3, 24,25,26,27) AX(P##4, 25,26,27,28) AX(P##5, 26,27,28,29) \
                 AX(P##6, 30,31,32,33) AX(P##7, 31,32,33,34) AX(P##8, 32,33,34,35) }

#define RED9(P, M) \
    P##0+=__shfl_xor(P##0,M); P##1+=__shfl_xor(P##1,M); P##2+=__shfl_xor(P##2,M); \
    P##3+=__shfl_xor(P##3,M); P##4+=__shfl_xor(P##4,M); P##5+=__shfl_xor(P##5,M); \
    P##6+=__shfl_xor(P##6,M); P##7+=__shfl_xor(P##7,M); P##8+=__shfl_xor(P##8,M);

#define S16(P0, P1, P2, P3) \
  (fabsf(v0.x-P0.x)+fabsf(v0.y-P0.y)+fabsf(v0.z-P0.z)+fabsf(v0.w-P0.w) \
  +fabsf(v1.x-P1.x)+fabsf(v1.y-P1.y)+fabsf(v1.z-P1.z)+fabsf(v1.w-P1.w) \
  +fabsf(v2.x-P2.x)+fabsf(v2.y-P2.y)+fabsf(v2.z-P2.z)+fabsf(v2.w-P2.w) \
  +fabsf(v3.x-P3.x)+fabsf(v3.y-P3.y)+fabsf(v3.z-P3.z)+fabsf(v3.w-P3.w))

// ===================== fused cooperative kernel (grid 256) =================
// Same structure as round 11 (correctness-proven) with register-pressure fix:
// #pragma unroll 1 on the two big-body loops in phase A (the 256-VGPR spill
// source). Everything else untouched.
__global__ __launch_bounds__(256) void fused_kernel(
    const float* __restrict__ readout, const float* __restrict__ energy,
    const float* __restrict__ w1, const float* __restrict__ w2,
    const float* __restrict__ Tm, const float* __restrict__ W1,
    const float* __restrict__ b1v, const float* __restrict__ W2,
    const float* __restrict__ b2v,
    float* __restrict__ f_ws, float* __restrict__ Mw,
    float* __restrict__ o_part, float* __restrict__ W1T,
    float* __restrict__ out)
{
    __shared__ float smem[4576];         // 18.3 KB, aliased per phase
    const int bid = blockIdx.x;
    const int t = threadIdx.x;
    cg::grid_group grid = cg::this_grid();

    // ---------------- Phase A: conv stack, samples 2*bid, 2*bid+1 ---------
    {
        float* ro = smem;                // [2][81]
        float* h1 = smem + 192;          // [2][1152]

        if (t < 162) ro[t] = readout[bid*162 + t];
        __syncthreads();

        if (t < 128) {                   // reco_energy
            const int es = t >> 6, l = t & 63;
            float v = ro[es*81 + l];
            if (l < 17) v += ro[es*81 + l + 64];
            #pragma unroll
            for (int m = 32; m; m >>= 1) v += __shfl_down(v, m);
            if (l == 0) f_ws[(2*bid+es)*577 + 576] = fabsf(v - energy[2*bid+es]);
        }

        #pragma unroll 1
        for (int idx = t; idx < 384; idx += 256) {   // conv1 (keep body single)
            const int sA = (idx >= 192) ? 1 : 0;
            const int rem = idx - sA*192;
            const int oc1 = rem & 31, y = rem >> 5;
            const float* rp = ro + sA*81;
            const float4* wp4 = (const float4*)&w1[oc1*16];
            const float4 wa = wp4[0], wb = wp4[1], wc = wp4[2], wd = wp4[3];
            const int rb0 = y*9;
            ROROW(A, rb0)
            ROROW(B, rb0+9)
            ROROW(C, rb0+18)
            ROROW(D, rb0+27)
            float* hp = &h1[sA*1152 + oc1*36 + y*6];
            float v;
            v = C1X(0,1,2,3); hp[0] = LRELU(v);
            v = C1X(1,2,3,4); hp[1] = LRELU(v);
            v = C1X(2,3,4,5); hp[2] = LRELU(v);
            v = C1X(3,4,5,6); hp[3] = LRELU(v);
            v = C1X(4,5,6,7); hp[4] = LRELU(v);
            v = C1X(5,6,7,8); hp[5] = LRELU(v);
        }
        __syncthreads();

        // conv2: s2 = t>>7, ocp = (t&127)>>2 (2 oc), ich = t&3 (8 ic each)
        const int s2 = t >> 7, lt = t & 127;
        const int ocp = lt >> 2, ich = t & 3;
        const int oca = ocp*2, ocbb = oca + 1;
        float a0=0.f,a1=0.f,a2=0.f,a3=0.f,a4=0.f,a5=0.f,a6=0.f,a7=0.f,a8=0.f;
        float g0=0.f,g1=0.f,g2=0.f,g3=0.f,g4=0.f,g5=0.f,g6=0.f,g7=0.f,g8=0.f;
        const float* hb = h1 + s2*1152;
        #pragma unroll 1
        for (int k = 0; k < 8; k++) {    // DO NOT unroll: 8x body = 256 VGPR
            const int ic = ich + k*4;
            const float4* hp = (const float4*)&hb[ic*36];
            const float4 q0=hp[0], q1=hp[1], q2=hp[2], q3=hp[3], q4=hp[4],
                         q5=hp[5], q6=hp[6], q7=hp[7], q8=hp[8];
            const float4* wpa = (const float4*)&w2[oca*512 + ic*16];
            const float4* wpb = (const float4*)&w2[ocbb*512 + ic*16];
            { float4 w = wpa[0]; KY0(a) }
            { float4 w = wpa[1]; KY1(a) }
            { float4 w = wpa[2]; KY2(a) }
            { float4 w = wpa[3]; KY3(a) }
            { float4 w = wpb[0]; KY0(g) }
            { float4 w = wpb[1]; KY1(g) }
            { float4 w = wpb[2]; KY2(g) }
            { float4 w = wpb[3]; KY3(g) }
        }
        RED9(a,1) RED9(a,2) RED9(g,1) RED9(g,2)

        if (ich == 0) {
            const int n = 2*bid + s2;
            float* fa = &f_ws[n*577 + oca*9];
            float* fb = &f_ws[n*577 + ocbb*9];
            float v;
            v=a0; fa[0]=LRELU(v); v=a1; fa[1]=LRELU(v); v=a2; fa[2]=LRELU(v);
            v=a3; fa[3]=LRELU(v); v=a4; fa[4]=LRELU(v); v=a5; fa[5]=LRELU(v);
            v=a6; fa[6]=LRELU(v); v=a7; fa[7]=LRELU(v); v=a8; fa[8]=LRELU(v);
            v=g0; fb[0]=LRELU(v); v=g1; fb[1]=LRELU(v); v=g2; fb[2]=LRELU(v);
            v=g3; fb[3]=LRELU(v); v=g4; fb[4]=LRELU(v); v=g5; fb[5]=LRELU(v);
            v=g6; fb[6]=LRELU(v); v=g7; fb[7]=LRELU(v); v=g8; fb[8]=LRELU(v);
        }

        if (bid < 8) {                   // W1 transpose
            for (int idx = t; idx < 2436; idx += 256) {
                const int g = bid*2436 + idx;
                const int u = g & 31, a = g >> 5;
                W1T[g] = W1[u*609 + a];
            }
        }
    }
    grid.sync();

    // ---------------- Phase B: M = F @ T, 2 tiles of (8r x 64c) -----------
    {
        float* redB = smem;              // [ks(4)][row(8)][col(64)]
        #pragma unroll 1
        for (int it = 0; it < 2; it++) {
            const int tt = bid*2 + it;
            const int rb = tt >> 3, cb = tt & 7;
            const int colB = cb*64 + (t & 63);
            const int r0B = rb*8;
            const int ks = __builtin_amdgcn_readfirstlane(t >> 6);
            const int k0 = ks*145;
            const int k1 = (k0 + 145 < 577) ? k0 + 145 : 577;
            float c0=0.f,c1=0.f,c2=0.f,c3=0.f,c4=0.f,c5=0.f,c6=0.f,c7=0.f;
            const float* fbase = f_ws + r0B*577;
            for (int k = k0; k < k1; ++k) {
                const float tv = Tm[k*512 + colB];
                const float* fr = fbase + k;
                c0 += fr[0]*tv;    c1 += fr[577]*tv;  c2 += fr[1154]*tv; c3 += fr[1731]*tv;
                c4 += fr[2308]*tv; c5 += fr[2885]*tv; c6 += fr[3462]*tv; c7 += fr[4039]*tv;
            }
            const int cl = t & 63;
            redB[ks*512 +   0 + cl] = c0;  redB[ks*512 +  64 + cl] = c1;
            redB[ks*512 + 128 + cl] = c2;  redB[ks*512 + 192 + cl] = c3;
            redB[ks*512 + 256 + cl] = c4;  redB[ks*512 + 320 + cl] = c5;
            redB[ks*512 + 384 + cl] = c6;  redB[ks*512 + 448 + cl] = c7;
            __syncthreads();
            for (int idx = t; idx < 512; idx += 256) {
                const float v = redB[idx] + redB[512+idx] + redB[1024+idx] + redB[1536+idx];
                Mw[(r0B + (idx >> 6))*512 + cb*64 + (idx & 63)] = v;
            }
            __syncthreads();
        }
    }
    grid.sync();

    // ---------------- Phase C: pairwise exp(-L1) --------------------------
    // jt = bid>>4 (32 j's), isp = bid&15 (32 i's, 4 chunks of 8)
    {
        const int jt  = bid >> 4;
        const int isp = bid & 15;
        const int b = t & 31, jl = t >> 5;
        const int j0 = jt * 32;
        float* mi = smem;                // 8 x 572 padded

        float4 mA0,mA1,mA2,mA3, mB0,mB1,mB2,mB3, mC0,mC1,mC2,mC3, mD0,mD1,mD2,mD3;
        { const float4* p_ = (const float4*)&Mw[(j0+jl   )*512 + b*16];
          mA0=p_[0]; mA1=p_[1]; mA2=p_[2]; mA3=p_[3]; }
        { const float4* p_ = (const float4*)&Mw[(j0+jl+ 8)*512 + b*16];
          mB0=p_[0]; mB1=p_[1]; mB2=p_[2]; mB3=p_[3]; }
        { const float4* p_ = (const float4*)&Mw[(j0+jl+16)*512 + b*16];
          mC0=p_[0]; mC1=p_[1]; mC2=p_[2]; mC3=p_[3]; }
        { const float4* p_ = (const float4*)&Mw[(j0+jl+24)*512 + b*16];
          mD0=p_[0]; mD1=p_[1]; mD2=p_[2]; mD3=p_[3]; }

        float acc0 = 0.f, acc1 = 0.f, acc2 = 0.f, acc3 = 0.f;
        const int lbase = b*16 + ((b>>1)<<2);

        #pragma unroll 1
        for (int chunk = 0; chunk < 4; chunk++) {
            const int i0 = isp*32 + chunk*8;
            #pragma unroll
            for (int k = 0; k < 4; k++) {
                const int q = k*256 + t;       // 0..1023
                const int r = q >> 7;
                const int x = (q & 127) * 4;
                float4 v = *(const float4*)&Mw[(i0+r)*512 + x];
                *(float4*)&mi[r*572 + x + ((x>>5)<<2)] = v;
            }
            __syncthreads();
            #pragma unroll
            for (int r = 0; r < 8; r++) {
                const float4* q_ = (const float4*)&mi[r*572 + lbase];
                const float4 v0 = q_[0], v1 = q_[1], v2 = q_[2], v3 = q_[3];
                acc0 += __expf(-(S16(mA0,mA1,mA2,mA3)));
                acc1 += __expf(-(S16(mB0,mB1,mB2,mB3)));
                acc2 += __expf(-(S16(mC0,mC1,mC2,mC3)));
                acc3 += __expf(-(S16(mD0,mD1,mD2,mD3)));
            }
            __syncthreads();
        }
        const int ob = isp*16384 + b;
        o_part[ob + (j0+jl   )*32] = acc0;
        o_part[ob + (j0+jl+8 )*32] = acc1;
        o_part[ob + (j0+jl+16)*32] = acc2;
        o_part[ob + (j0+jl+24)*32] = acc3;
    }
    grid.sync();

    // ---------------- Phase D: MLP head, samples 2*bid, 2*bid+1 -----------
    {
        float* xs   = smem;              // [2][640]
        float* redD = smem + 1280;       // [2][128]
        const int s2 = t >> 7, lt = t & 127;
        const int j = 2*bid + s2;
        const int u = lt & 31, gD = lt >> 5;   // gD in 0..3

        for (int a = lt; a < 577; a += 128) xs[s2*640 + a] = f_ws[j*577 + a];
        {
            float ov = 0.f;
            #pragma unroll
            for (int k = 0; k < 4; k++)
                ov += o_part[(gD + 4*k)*16384 + j*32 + u];
            redD[s2*128 + lt] = ov;
        }
        __syncthreads();
        if (lt < 32) {
            xs[s2*640 + 577 + lt] = redD[s2*128 + lt] + redD[s2*128 + lt + 32]
                                  + redD[s2*128 + lt + 64] + redD[s2*128 + lt + 96];
        }
        __syncthreads();

        float p = 0.f;
        #pragma unroll 4
        for (int a = gD; a < 609; a += 4)
            p += xs[s2*640 + a] * W1T[a*32 + u];
        redD[s2*128 + lt] = p;
        __syncthreads();

        if (lt < 32) {
            float hid = redD[s2*128 + lt] + redD[s2*128 + lt + 32]
                      + redD[s2*128 + lt + 64] + redD[s2*128 + lt + 96];
            hid += b1v[lt];
            hid = LRELU(hid);
            float pr = hid * W2[lt];
            #pragma unroll
            for (int mk = 16; mk; mk >>= 1) pr += __shfl_xor(pr, mk);
            if (lt == 0) out[j] = 1.f / (1.f + __expf(-(pr + b2v[0])));
        }
    }
}

// =================== fallback: round-9 four-kernel path ====================
__global__ __launch_bounds__(256) void convf_kernel(
    const float* __restrict__ readout, const float* __restrict__ energy,
    const float* __restrict__ w1, const float* __restrict__ w2,
    const float* __restrict__ W1, float* __restrict__ f_ws,
    float* __restrict__ W1T)
{
    const int bid = blockIdx.x;
    const int n   = bid >> 1;
    const int och = bid & 1;
    const int oc0 = och << 5;
    const int t = threadIdx.x;
    __shared__ float ro[81];
    __shared__ float h1[1152];

    if (t < 81) ro[t] = readout[n*81 + t];
    __syncthreads();

    if (och == 0 && t < 64) {
        float v = ro[t];
        if (t < 17) v += ro[t + 64];
        #pragma unroll
        for (int m = 32; m; m >>= 1) v += __shfl_down(v, m);
        if (t == 0) f_ws[n*577 + 576] = fabsf(v - energy[n]);
    }

    if (t < 192) {
        const int oc1 = t & 31, y = t >> 5;
        const float* rp = ro;
        const float4* wp4 = (const float4*)&w1[oc1*16];
        const float4 wa = wp4[0], wb = wp4[1], wc = wp4[2], wd = wp4[3];
        const int rb0 = y*9;
        ROROW(A, rb0)
        ROROW(B, rb0+9)
        ROROW(C, rb0+18)
        ROROW(D, rb0+27)
        float* hp = &h1[oc1*36 + y*6];
        float v;
        v = C1X(0,1,2,3); hp[0] = LRELU(v);
        v = C1X(1,2,3,4); hp[1] = LRELU(v);
        v = C1X(2,3,4,5); hp[2] = LRELU(v);
        v = C1X(3,4,5,6); hp[3] = LRELU(v);
        v = C1X(4,5,6,7); hp[4] = LRELU(v);
        v = C1X(5,6,7,8); hp[5] = LRELU(v);
    }
    __syncthreads();

    const int ocp = t >> 4, ich = t & 15;
    const int oca = oc0 + ocp*2, ocbb = oca + 1;
    float a0=0.f,a1=0.f,a2=0.f,a3=0.f,a4=0.f,a5=0.f,a6=0.f,a7=0.f,a8=0.f;
    float g0=0.f,g1=0.f,g2=0.f,g3=0.f,g4=0.f,g5=0.f,g6=0.f,g7=0.f,g8=0.f;

    #pragma unroll 1
    for (int k = 0; k < 2; k++) {
        const int ic = ich + k*16;
        const float4* hp = (const float4*)&h1[ic*36];
        const float4 q0=hp[0], q1=hp[1], q2=hp[2], q3=hp[3], q4=hp[4],
                     q5=hp[5], q6=hp[6], q7=hp[7], q8=hp[8];
        const float4* wpa = (const float4*)&w2[oca*512 + ic*16];
        const float4* wpb = (const float4*)&w2[ocbb*512 + ic*16];
        { float4 w = wpa[0]; KY0(a) }
        { float4 w = wpa[1]; KY1(a) }
        { float4 w = wpa[2]; KY2(a) }
        { float4 w = wpa[3]; KY3(a) }
        { float4 w = wpb[0]; KY0(g) }
        { float4 w = wpb[1]; KY1(g) }
        { float4 w = wpb[2]; KY2(g) }
        { float4 w = wpb[3]; KY3(g) }
    }
    RED9(a,1) RED9(a,2) RED9(a,4) RED9(a,8)
    RED9(g,1) RED9(g,2) RED9(g,4) RED9(g,8)

    if (ich == 0) {
        float* fa = &f_ws[n*577 + oca*9];
        float* fb = &f_ws[n*577 + ocbb*9];
        float v;
        v=a0; fa[0]=LRELU(v); v=a1; fa[1]=LRELU(v); v=a2; fa[2]=LRELU(v);
        v=a3; fa[3]=LRELU(v); v=a4; fa[4]=LRELU(v); v=a5; fa[5]=LRELU(v);
        v=a6; fa[6]=LRELU(v); v=a7; fa[7]=LRELU(v); v=a8; fa[8]=LRELU(v);
        v=g0; fb[0]=LRELU(v); v=g1; fb[1]=LRELU(v); v=g2; fb[2]=LRELU(v);
        v=g3; fb[3]=LRELU(v); v=g4; fb[4]=LRELU(v); v=g5; fb[5]=LRELU(v);
        v=g6; fb[6]=LRELU(v); v=g7; fb[7]=LRELU(v); v=g8; fb[8]=LRELU(v);
    }

    if (bid < 8) {
        for (int idx = t; idx < 2436; idx += 256) {
            const int g = bid*2436 + idx;
            const int u = g & 31, a = g >> 5;
            W1T[g] = W1[u*609 + a];
        }
    }
}

__global__ __launch_bounds__(256) void mgemm_kernel(
    const float* __restrict__ F, const float* __restrict__ T,
    float* __restrict__ M)
{
    const int rb = blockIdx.x >> 3;
    const int cb = blockIdx.x & 7;
    const int t = threadIdx.x;
    const int col = cb*64 + (t & 63);
    const int r0 = rb*8 + (t >> 6)*2;
    const int r0u = __builtin_amdgcn_readfirstlane(r0);
    const float* f0 = F + r0u*577;
    const float* f1 = f0 + 577;
    const float* Tc = T + col;
    float a0 = 0.f, a1 = 0.f;
    #pragma unroll 4
    for (int a = 0; a < 576; a += 4) {
        const float t0 = Tc[(a+0)*512];
        const float t1 = Tc[(a+1)*512];
        const float t2 = Tc[(a+2)*512];
        const float t3 = Tc[(a+3)*512];
        a0 += f0[a]*t0 + f0[a+1]*t1 + f0[a+2]*t2 + f0[a+3]*t3;
        a1 += f1[a]*t0 + f1[a+1]*t1 + f1[a+2]*t2 + f1[a+3]*t3;
    }
    {
        const float tv = Tc[576*512];
        a0 += f0[576]*tv;
        a1 += f1[576]*tv;
    }
    M[(r0+0)*512 + col] = a0;
    M[(r0+1)*512 + col] = a1;
}

__global__ __launch_bounds__(256) void pairwise_kernel(
    const float* __restrict__ Mw, float* __restrict__ o_part) // (16,512,32)
{
    const int jt  = blockIdx.x >> 4;
    const int isp = blockIdx.x & 15;
    const int t = threadIdx.x;
    const int b = t & 31, jl = t >> 5;
    const int j0 = jt * 32;
    __shared__ float mi[8*572];

    float4 mA0,mA1,mA2,mA3, mB0,mB1,mB2,mB3, mC0,mC1,mC2,mC3, mD0,mD1,mD2,mD3;
    { const float4* p_ = (const float4*)&Mw[(j0+jl   )*512 + b*16];
      mA0=p_[0]; mA1=p_[1]; mA2=p_[2]; mA3=p_[3]; }
    { const float4* p_ = (const float4*)&Mw[(j0+jl+ 8)*512 + b*16];
      mB0=p_[0]; mB1=p_[1]; mB2=p_[2]; mB3=p_[3]; }
    { const float4* p_ = (const float4*)&Mw[(j0+jl+16)*512 + b*16];
      mC0=p_[0]; mC1=p_[1]; mC2=p_[2]; mC3=p_[3]; }
    { const float4* p_ = (const float4*)&Mw[(j0+jl+24)*512 + b*16];
      mD0=p_[0]; mD1=p_[1]; mD2=p_[2]; mD3=p_[3]; }

    float acc0 = 0.f, acc1 = 0.f, acc2 = 0.f, acc3 = 0.f;
    const int lbase = b*16 + ((b>>1)<<2);

    for (int chunk = 0; chunk < 4; chunk++) {
        const int i0 = isp*32 + chunk*8;
        #pragma unroll
        for (int k = 0; k < 4; k++) {
            const int q = k*256 + t;
            const int r = q >> 7;
            const int x = (q & 127) * 4;
            float4 v = *(const float4*)&Mw[(i0+r)*512 + x];
            *(float4*)&mi[r*572 + x + ((x>>5)<<2)] = v;
        }
        __syncthreads();
        #pragma unroll
        for (int r = 0; r < 8; r++) {
            const float4* q_ = (const float4*)&mi[r*572 + lbase];
            const float4 v0 = q_[0], v1 = q_[1], v2 = q_[2], v3 = q_[3];
            acc0 += __expf(-(S16(mA0,mA1,mA2,mA3)));
            acc1 += __expf(-(S16(mB0,mB1,mB2,mB3)));
            acc2 += __expf(-(S16(mC0,mC1,mC2,mC3)));
            acc3 += __expf(-(S16(mD0,mD1,mD2,mD3)));
        }
        __syncthreads();
    }
    const int ob = isp*16384 + b;
    o_part[ob + (j0+jl   )*32] = acc0;
    o_part[ob + (j0+jl+8 )*32] = acc1;
    o_part[ob + (j0+jl+16)*32] = acc2;
    o_part[ob + (j0+jl+24)*32] = acc3;
}

__global__ __launch_bounds__(256) void mlp_kernel(
    const float* __restrict__ f, const float* __restrict__ o_part,
    const float* __restrict__ W1T, const float* __restrict__ b1v,
    const float* __restrict__ W2, const float* __restrict__ b2v,
    float* __restrict__ out)
{
    const int j = blockIdx.x;
    const int t = threadIdx.x;
    __shared__ float xs[609];
    __shared__ float red[256];

    for (int a = t; a < 577; a += 256) xs[a] = f[j*577 + a];
    {
        const int bb = t & 31, g = t >> 5;
        float ov = 0.f;
        #pragma unroll
        for (int k = 0; k < 2; k++)
            ov += o_part[(g + 8*k)*16384 + j*32 + bb];
        red[t] = ov;
    }
    __syncthreads();
    if (t < 32) {
        float ov = 0.f;
        #pragma unroll
        for (int g = 0; g < 8; g++) ov += red[t + g*32];
        xs[577 + t] = ov;
    }
    __syncthreads();

    const int u = t & 31, seg = t >> 5;
    float p = 0.f;
    #pragma unroll 4
    for (int a = seg; a < 609; a += 8)
        p += xs[a] * W1T[a*32 + u];
    red[t] = p;
    __syncthreads();

    if (t < 32) {
        float hid = red[t];
        #pragma unroll
        for (int s = 1; s < 8; s++) hid += red[t + s*32];
        hid += b1v[t];
        hid = LRELU(hid);
        float pr = hid * W2[t];
        #pragma unroll
        for (int mk = 16; mk; mk >>= 1) pr += __shfl_xor(pr, mk);
        if (t == 0) out[j] = 1.f / (1.f + __expf(-(pr + b2v[0])));
    }
}

extern "C" void kernel_launch(void* const* d_in, const int* in_sizes, int n_in,
                              void* d_out, int out_size, void* d_ws, size_t ws_size,
                              hipStream_t stream) {
    const float* readout = (const float*)d_in[0];
    const float* energy  = (const float*)d_in[1];
    const float* w1      = (const float*)d_in[2];
    const float* w2      = (const float*)d_in[3];
    const float* Tm      = (const float*)d_in[4];
    const float* W1      = (const float*)d_in[5];
    const float* b1v     = (const float*)d_in[6];
    const float* W2      = (const float*)d_in[7];
    const float* b2v     = (const float*)d_in[8];
    float* out = (float*)d_out;

    char* ws = (char*)d_ws;
    float* f_ws   = (float*)(ws);                                       // 512*577
    float* M_ws   = (float*)(ws + 512*577*4);                           // 512*512
    float* o_ws   = (float*)(ws + 512*577*4 + 512*512*4);               // 16*512*32
    float* W1T_ws = (float*)(ws + 512*577*4 + 512*512*4 + 16*512*32*4); // 609*32

    void* args[] = {
        (void*)&readout, (void*)&energy, (void*)&w1, (void*)&w2, (void*)&Tm,
        (void*)&W1, (void*)&b1v, (void*)&W2, (void*)&b2v,
        (void*)&f_ws, (void*)&M_ws, (void*)&o_ws, (void*)&W1T_ws, (void*)&out
    };
    hipError_t err = hipLaunchCooperativeKernel((void*)fused_kernel, dim3(256),
                                                dim3(256), args, 0, stream);
    if (err != hipSuccess) {
        convf_kernel   <<<1024, 256, 0, stream>>>(readout, energy, w1, w2, W1, f_ws, W1T_ws);
        mgemm_kernel   <<<512, 256, 0, stream>>>(f_ws, Tm, M_ws);
        pairwise_kernel<<<256, 256, 0, stream>>>(M_ws, o_ws);
        mlp_kernel     <<<512, 256, 0, stream>>>(f_ws, o_ws, W1T_ws, b1v, W2, b2v, out);
    }
}